// Round 8
// baseline (204.667 us; speedup 1.0000x reference)
//
#include <hip/hip_runtime.h>
#include <hip/hip_bf16.h>

#define Tsz 2048
#define Csz 1024
#define Hn 16

typedef short s8v __attribute__((ext_vector_type(8)));
typedef short s4v __attribute__((ext_vector_type(4)));
typedef float f4v __attribute__((ext_vector_type(4)));

#define QSCALE (0.125f * 1.44269504088896f)  // 1/sqrt(64) * log2(e), folded into Q

__device__ __forceinline__ short bf_bits(float x) {
    __hip_bfloat16 t = __float2bfloat16(x);
    return *reinterpret_cast<short*>(&t);
}

__device__ __forceinline__ void gload_lds(const void* g, void* l) {
    __builtin_amdgcn_global_load_lds(
        (const __attribute__((address_space(1))) void*)g,
        (__attribute__((address_space(3))) void*)l, 16, 0, 0);
}

// ---------------- fp32 -> bf16 conversion, exact-size grid (8192 blocks) ----------------
__global__ void cvt6(const float* __restrict__ x, const float* __restrict__ wq,
                     const float* __restrict__ wk, const float* __restrict__ wv,
                     const float* __restrict__ wp,
                     short* __restrict__ xo, short* __restrict__ qo,
                     short* __restrict__ ko, short* __restrict__ vo,
                     short* __restrict__ po) {
    const int bx = blockIdx.x;
    const float* in; short* out; int ib;
    if (bx < 4096) { in = x; out = xo; ib = bx; }
    else {
        const int r = bx - 4096, w = r >> 10;
        ib = r & 1023;
        switch (w) {
            case 0: in = wq; out = qo; break;
            case 1: in = wk; out = ko; break;
            case 2: in = wv; out = vo; break;
            default: in = wp; out = po; break;
        }
    }
    const int i = ib * 1024 + threadIdx.x * 4;
    float4 v = *(const float4*)(in + i);
    short4 o;
    o.x = bf_bits(v.x); o.y = bf_bits(v.y); o.z = bf_bits(v.z); o.w = bf_bits(v.w);
    *(short4*)(out + i) = o;
}

// ---------------- fused QKV GEMM (m97 structure) ----------------
// out[m,n] = sum_k X[m,k]*W[n,k] + b[n].  BM=BN=128, BK=32, 256 thr, wave=64x64.
// z=0: Q (bf16, *QSCALE), z=1: K (bf16), z=2: V -> Vt[(b*1024+ch)*T + t] (bf16,
// via LDS-transpose epilogue with coalesced stores).
// launch_bounds (256,2): (256,3) caps VGPR at ~168 -> likely scratch spill with
// 64-AGPR accumulator + epilogue state; (256,2) releases to 256.
__global__ __launch_bounds__(256, 2) void qkv_gemm(
    const short* __restrict__ X,
    const short* __restrict__ Wq, const short* __restrict__ Wk, const short* __restrict__ Wv,
    const float* __restrict__ bq, const float* __restrict__ bk, const float* __restrict__ bv,
    short* __restrict__ Qo, short* __restrict__ Ko, short* __restrict__ Vto)
{
    const int z = blockIdx.z;
    const short* W = (z == 0) ? Wq : (z == 1) ? Wk : Wv;
    const float* bias = (z == 0) ? bq : (z == 1) ? bk : bv;

    __shared__ __align__(16) short Ash[128 * 32];
    __shared__ __align__(16) short Bsh[128 * 32];
    __shared__ __align__(16) short TR[64 * 72];   // transpose staging (z==2 epilogue)

    const int tid = threadIdx.x, lane = tid & 63, wave = tid >> 6;
    const int ln = lane & 15, hi = lane >> 4;
    const int m0 = blockIdx.x * 128, n0 = blockIdx.y * 128;
    const int wm = (wave >> 1) * 64, wn = (wave & 1) * 64;

    const short* Ag = X + (size_t)(m0 + (tid >> 2)) * Csz + (tid & 3) * 8;
    const short* Bg = W + (size_t)(n0 + (tid >> 2)) * Csz + (tid & 3) * 8;

    f4v acc[4][4];
    #pragma unroll
    for (int mt = 0; mt < 4; mt++)
        #pragma unroll
        for (int nt = 0; nt < 4; nt++)
            #pragma unroll
            for (int i = 0; i < 4; i++) acc[mt][nt][i] = 0.f;

    for (int k0 = 0; k0 < Csz; k0 += 32) {
        __syncthreads();
        gload_lds(Ag + k0, Ash + tid * 8);
        gload_lds(Ag + k0 + (size_t)64 * Csz, Ash + 2048 + tid * 8);
        gload_lds(Bg + k0, Bsh + tid * 8);
        gload_lds(Bg + k0 + (size_t)64 * Csz, Bsh + 2048 + tid * 8);
        __syncthreads();

        s8v af[4], bfr[4];
        #pragma unroll
        for (int mt = 0; mt < 4; mt++)
            af[mt] = *(const s8v*)(Ash + (wm + mt * 16 + ln) * 32 + hi * 8);
        #pragma unroll
        for (int nt = 0; nt < 4; nt++)
            bfr[nt] = *(const s8v*)(Bsh + (wn + nt * 16 + ln) * 32 + hi * 8);
        #pragma unroll
        for (int mt = 0; mt < 4; mt++)
            #pragma unroll
            for (int nt = 0; nt < 4; nt++)
                acc[mt][nt] = __builtin_amdgcn_mfma_f32_16x16x32_bf16(af[mt], bfr[nt], acc[mt][nt], 0, 0, 0);
    }

    if (z == 2) {
        // LDS-transpose epilogue: 4 passes, each pass covers (m-half, n-half).
        const int b = m0 >> 11, t0 = m0 & 2047;
        float bvv[4];
        #pragma unroll
        for (int nt = 0; nt < 4; nt++) bvv[nt] = bias[n0 + wn + nt * 16 + ln];
        #pragma unroll
        for (int ph = 0; ph < 4; ph++) {
            const int mh = ph >> 1, nh = ph & 1;
            __syncthreads();
            if ((wave >> 1) == mh && (wave & 1) == nh) {
                #pragma unroll
                for (int mt = 0; mt < 4; mt++)
                    #pragma unroll
                    for (int nt = 0; nt < 4; nt++) {
                        s4v pk;
                        #pragma unroll
                        for (int i = 0; i < 4; i++) pk[i] = bf_bits(acc[mt][nt][i] + bvv[nt]);
                        *(s4v*)(TR + (nt * 16 + ln) * 72 + mt * 16 + hi * 4) = pk;
                    }
            }
            __syncthreads();
            const int chl = tid >> 2, seg = tid & 3;   // 64 ch rows x 4 t-segments
            const s8v r0 = *(const s8v*)(TR + chl * 72 + seg * 16);
            const s8v r1 = *(const s8v*)(TR + chl * 72 + seg * 16 + 8);
            short* dst = Vto + (size_t)(b * 1024 + n0 + nh * 64 + chl) * Tsz + t0 + mh * 64 + seg * 16;
            *(s8v*)(dst) = r0;
            *(s8v*)(dst + 8) = r1;
        }
        return;
    }

    const float scale = (z == 0) ? QSCALE : 1.0f;
    short* out = (z == 0) ? Qo : Ko;

    #pragma unroll
    for (int nt = 0; nt < 4; nt++) {
        const int col = n0 + wn + nt * 16 + ln;
        const float bvv = bias[col];
        #pragma unroll
        for (int mt = 0; mt < 4; mt++) {
            const int row0 = m0 + wm + mt * 16 + hi * 4;
            #pragma unroll
            for (int i = 0; i < 4; i++)
                out[(size_t)(row0 + i) * Csz + col] = bf_bits((acc[mt][nt][i] + bvv) * scale);
        }
    }
}

// ---------------- output projection GEMM (f32 out), 128x128 tiles ----------------
__global__ __launch_bounds__(256, 2) void proj_gemm(
    const short* __restrict__ A, const short* __restrict__ W,
    const float* __restrict__ bias, float* __restrict__ out)
{
    __shared__ __align__(16) short Ash[128 * 32];
    __shared__ __align__(16) short Bsh[128 * 32];

    const int tid = threadIdx.x, lane = tid & 63, wave = tid >> 6;
    const int ln = lane & 15, hi = lane >> 4;
    const int m0 = blockIdx.x * 128, n0 = blockIdx.y * 128;
    const int wm = (wave >> 1) * 64, wn = (wave & 1) * 64;

    const short* Ag = A + (size_t)(m0 + (tid >> 2)) * Csz + (tid & 3) * 8;
    const short* Bg = W + (size_t)(n0 + (tid >> 2)) * Csz + (tid & 3) * 8;

    f4v acc[4][4];
    #pragma unroll
    for (int mt = 0; mt < 4; mt++)
        #pragma unroll
        for (int nt = 0; nt < 4; nt++)
            #pragma unroll
            for (int i = 0; i < 4; i++) acc[mt][nt][i] = 0.f;

    for (int k0 = 0; k0 < Csz; k0 += 32) {
        __syncthreads();
        gload_lds(Ag + k0, Ash + tid * 8);
        gload_lds(Ag + k0 + (size_t)64 * Csz, Ash + 2048 + tid * 8);
        gload_lds(Bg + k0, Bsh + tid * 8);
        gload_lds(Bg + k0 + (size_t)64 * Csz, Bsh + 2048 + tid * 8);
        __syncthreads();

        s8v af[4], bfr[4];
        #pragma unroll
        for (int mt = 0; mt < 4; mt++)
            af[mt] = *(const s8v*)(Ash + (wm + mt * 16 + ln) * 32 + hi * 8);
        #pragma unroll
        for (int nt = 0; nt < 4; nt++)
            bfr[nt] = *(const s8v*)(Bsh + (wn + nt * 16 + ln) * 32 + hi * 8);
        #pragma unroll
        for (int mt = 0; mt < 4; mt++)
            #pragma unroll
            for (int nt = 0; nt < 4; nt++)
                acc[mt][nt] = __builtin_amdgcn_mfma_f32_16x16x32_bf16(af[mt], bfr[nt], acc[mt][nt], 0, 0, 0);
    }

    #pragma unroll
    for (int nt = 0; nt < 4; nt++) {
        const int col = n0 + wn + nt * 16 + ln;
        const float bvv = bias[col];
        #pragma unroll
        for (int mt = 0; mt < 4; mt++)
            #pragma unroll
            for (int i = 0; i < 4; i++)
                out[(size_t)(m0 + wm + mt * 16 + hi * 4 + i) * Csz + col] = acc[mt][nt][i] + bvv;
    }
}

// ---------------- Flash attention v8 (32 q-rows per wave: 2:1 MFMA:ds_read) ----------
// Q,K: [B,T,C] bf16; Vt: [B*H*64, T] bf16; Y: [B,T,C] bf16.
// St = K*Q^T, O^T = Vt*P^T; P^T re-laid out via wave-private LDS.
// Block: 4 waves; waves 0-1 own q-tile p (rows 0-31 / 32-63), waves 2-3 own
// tile 31-p. Each wave: 64 keys x 32 q per iter = 32 MFMA from 16 kf/vf reads.
// K/V LDS double-buffered: one __syncthreads per key-tile iteration.
__global__ __launch_bounds__(256, 2) void attn8(
    const short* __restrict__ Q, const short* __restrict__ Kg,
    const short* __restrict__ Vt, short* __restrict__ Y)
{
    __shared__ __align__(16) short Ksh[2][64 * 72];  // [buf][key][d], pitch 72
    __shared__ __align__(16) short Vsh[2][64 * 72];  // [buf][d][key], pitch 72
    __shared__ __align__(16) short Psh[4][32 * 72];  // per-wave Pq[q][key]

    const int tid = threadIdx.x, lane = tid & 63, wave = tid >> 6;
    const int ln = lane & 15, hi = lane >> 4;
    const int p = blockIdx.x;                 // pair 0..15
    const int qt = (wave >> 1) ? (31 - p) : p; // this wave's 64-row q-tile
    const int qh = wave & 1;                   // which 32-row half
    const int q0 = qt * 64 + qh * 32;
    const int bh = blockIdx.y;
    const size_t base = (size_t)(bh >> 4) * Tsz * Csz + (size_t)(bh & 15) * 64;
    const size_t vtbase = (size_t)bh * 64 * Tsz;
    short* Pq = Psh[wave];

    // Q fragments: qf[j][kk] covers q rows q0 + j*16 + ln, k-slice kk*32+hi*8
    s8v qf[2][2];
    #pragma unroll
    for (int j = 0; j < 2; j++)
        #pragma unroll
        for (int kk = 0; kk < 2; kk++)
            qf[j][kk] = *(const s8v*)(Q + base + (size_t)(q0 + j * 16 + ln) * Csz + kk * 32 + hi * 8);

    f4v o[2][4];
    float lsum[2] = {0.f, 0.f};
    #pragma unroll
    for (int j = 0; j < 2; j++)
        #pragma unroll
        for (int dt = 0; dt < 4; dt++)
            #pragma unroll
            for (int i = 0; i < 4; i++) o[j][dt][i] = 0.f;

    // staging: 256 threads, each 32 B of K and 32 B of V per tile
    const int sr = tid >> 2, sc = (tid & 3) * 16;
    const short* Kp = Kg + base + (size_t)sr * Csz + sc;
    const short* Vp = Vt + vtbase + (size_t)sr * Tsz + sc;
    const int swo = sr * 72 + sc;

    const int nkb = 32 - p;

    // prologue: tile0 -> buf0; prefetch tile1 into regs
    s8v kR0 = *(const s8v*)(Kp);
    s8v kR1 = *(const s8v*)(Kp + 8);
    s8v vR0 = *(const s8v*)(Vp);
    s8v vR1 = *(const s8v*)(Vp + 8);
    *(s8v*)(&Ksh[0][swo]) = kR0; *(s8v*)(&Ksh[0][swo + 8]) = kR1;
    *(s8v*)(&Vsh[0][swo]) = vR0; *(s8v*)(&Vsh[0][swo + 8]) = vR1;
    kR0 = *(const s8v*)(Kp + (size_t)64 * Csz);
    kR1 = *(const s8v*)(Kp + (size_t)64 * Csz + 8);
    vR0 = *(const s8v*)(Vp + 64);
    vR1 = *(const s8v*)(Vp + 64 + 8);
    __syncthreads();

    for (int kb = 0; kb < nkb; kb++) {
        const int buf = kb & 1;
        if (kb + 1 < nkb) {
            *(s8v*)(&Ksh[buf ^ 1][swo]) = kR0; *(s8v*)(&Ksh[buf ^ 1][swo + 8]) = kR1;
            *(s8v*)(&Vsh[buf ^ 1][swo]) = vR0; *(s8v*)(&Vsh[buf ^ 1][swo + 8]) = vR1;
            const int knx = (kb + 2 < nkb) ? (kb + 2) * 64 : (nkb - 1) * 64;
            kR0 = *(const s8v*)(Kp + (size_t)knx * Csz);
            kR1 = *(const s8v*)(Kp + (size_t)knx * Csz + 8);
            vR0 = *(const s8v*)(Vp + knx);
            vR1 = *(const s8v*)(Vp + knx + 8);
        }

        if (kb <= qt) {                        // wave-uniform activity
            s8v kf[2][4], vf[2][4];
            #pragma unroll
            for (int nt = 0; nt < 4; nt++)
                #pragma unroll
                for (int kk = 0; kk < 2; kk++) {
                    kf[kk][nt] = *(const s8v*)(&Ksh[buf][(nt * 16 + ln) * 72 + kk * 32 + hi * 8]);
                    vf[kk][nt] = *(const s8v*)(&Vsh[buf][(nt * 16 + ln) * 72 + kk * 32 + hi * 8]);
                }

            const bool dg = (kb == qt);

            // S^T: 64 keys x 32 q = 16 MFMA
            f4v s[4][2];
            #pragma unroll
            for (int nt = 0; nt < 4; nt++)
                #pragma unroll
                for (int j = 0; j < 2; j++) {
                    #pragma unroll
                    for (int i = 0; i < 4; i++) s[nt][j][i] = 0.f;
                    s[nt][j] = __builtin_amdgcn_mfma_f32_16x16x32_bf16(kf[0][nt], qf[j][0], s[nt][j], 0, 0, 0);
                    s[nt][j] = __builtin_amdgcn_mfma_f32_16x16x32_bf16(kf[1][nt], qf[j][1], s[nt][j], 0, 0, 0);
                }

            // exp2 + mask + P^T write (lane holds keys nt*16+hi*4+{0..3}, q=j*16+ln)
            #pragma unroll
            for (int nt = 0; nt < 4; nt++)
                #pragma unroll
                for (int j = 0; j < 2; j++) {
                    float pv[4];
                    #pragma unroll
                    for (int i = 0; i < 4; i++) pv[i] = exp2f(s[nt][j][i]);
                    if (dg) {
                        const int kr = nt * 16 + hi * 4;
                        const int qr = qh * 32 + j * 16 + ln;
                        #pragma unroll
                        for (int i = 0; i < 4; i++)
                            if (kr + i > qr) pv[i] = 0.f;
                    }
                    lsum[j] += (pv[0] + pv[1]) + (pv[2] + pv[3]);
                    s4v w;
                    #pragma unroll
                    for (int i = 0; i < 4; i++) w[i] = bf_bits(pv[i]);
                    *(s4v*)(Pq + (j * 16 + ln) * 72 + nt * 16 + hi * 4) = w;
                }

            // B-frag reads: keys kk*32+hi*8+{0..7} for q col j*16+ln
            s8v pb[2][2];
            #pragma unroll
            for (int j = 0; j < 2; j++)
                #pragma unroll
                for (int kk = 0; kk < 2; kk++)
                    pb[j][kk] = *(const s8v*)(Pq + (j * 16 + ln) * 72 + kk * 32 + hi * 8);

            // O^T: 64 d x 32 q = 16 MFMA
            #pragma unroll
            for (int dt = 0; dt < 4; dt++)
                #pragma unroll
                for (int j = 0; j < 2; j++) {
                    o[j][dt] = __builtin_amdgcn_mfma_f32_16x16x32_bf16(vf[0][dt], pb[j][0], o[j][dt], 0, 0, 0);
                    o[j][dt] = __builtin_amdgcn_mfma_f32_16x16x32_bf16(vf[1][dt], pb[j][1], o[j][dt], 0, 0, 0);
                }
        }
        __syncthreads();
    }

    // l per q col: reduce lsum across the 4 hi-groups (lanes ln+16k)
    #pragma unroll
    for (int j = 0; j < 2; j++) {
        float l = lsum[j];
        l += __shfl_xor(l, 16);
        l += __shfl_xor(l, 32);
        const float inv = 1.0f / l;
        const int qrow = q0 + j * 16 + ln;
        #pragma unroll
        for (int dt = 0; dt < 4; dt++) {
            s4v w;
            #pragma unroll
            for (int i = 0; i < 4; i++) w[i] = bf_bits(o[j][dt][i] * inv);
            *(s4v*)(Y + base + (size_t)qrow * Csz + dt * 16 + hi * 4) = w;
        }
    }
}

extern "C" void kernel_launch(void* const* d_in, const int* in_sizes, int n_in,
                              void* d_out, int out_size, void* d_ws, size_t ws_size,
                              hipStream_t stream) {
    const float* x  = (const float*)d_in[0];
    const float* Wq = (const float*)d_in[1];
    const float* bq = (const float*)d_in[2];
    const float* Wk = (const float*)d_in[3];
    const float* bk = (const float*)d_in[4];
    const float* Wv = (const float*)d_in[5];
    const float* bv = (const float*)d_in[6];
    const float* Wp = (const float*)d_in[7];
    const float* bp = (const float*)d_in[8];

    char* ws = (char*)d_ws;
    short* Xb  = (short*)(ws);                 // 8 MB
    short* Wqb = (short*)(ws + (8u  << 20));   // 2 MB each
    short* Wkb = (short*)(ws + (10u << 20));
    short* Wvb = (short*)(ws + (12u << 20));
    short* Wpb = (short*)(ws + (14u << 20));
    short* Qb  = (short*)(ws + (16u << 20));   // 8 MB each
    short* Kb  = (short*)(ws + (24u << 20));
    short* Vtb = (short*)(ws + (32u << 20));   // V transposed per head [B*H*64, T]
    short* Yb  = (short*)(ws + (40u << 20));

    hipLaunchKernelGGL(cvt6, dim3(8192), dim3(256), 0, stream,
                       x, Wq, Wk, Wv, Wp, Xb, Wqb, Wkb, Wvb, Wpb);

    hipLaunchKernelGGL(qkv_gemm, dim3(32, 8, 3), dim3(256), 0, stream,
                       Xb, Wqb, Wkb, Wvb, bq, bk, bv, Qb, Kb, Vtb);

    hipLaunchKernelGGL(attn8, dim3(16, 32), dim3(256), 0, stream, Qb, Kb, Vtb, Yb);

    hipLaunchKernelGGL(proj_gemm, dim3(32, 8), dim3(256), 0, stream, Yb, Wpb, bp, (float*)d_out);
}

// Round 9
// 189.139 us; speedup vs baseline: 1.0821x; 1.0821x over previous
//
#include <hip/hip_runtime.h>
#include <hip/hip_bf16.h>

#define Tsz 2048
#define Csz 1024
#define Hn 16

typedef short s8v __attribute__((ext_vector_type(8)));
typedef short s4v __attribute__((ext_vector_type(4)));
typedef float f4v __attribute__((ext_vector_type(4)));

#define QSCALE (0.125f * 1.44269504088896f)  // 1/sqrt(64) * log2(e), folded into Q

// fast bf16 round (bits+0x8000)>>16 : 2 VALU vs ~6 for software RNE
__device__ __forceinline__ unsigned short bfr(float x) {
    return (unsigned short)((__builtin_bit_cast(unsigned, x) + 0x8000u) >> 16);
}
__device__ __forceinline__ unsigned pack2_rn(float a, float b) {
    const unsigned ua = __builtin_bit_cast(unsigned, a) + 0x8000u;
    const unsigned ub = __builtin_bit_cast(unsigned, b) + 0x8000u;
    return (ua >> 16) | (ub & 0xFFFF0000u);
}

__device__ __forceinline__ void gload_lds(const void* g, void* l) {
    __builtin_amdgcn_global_load_lds(
        (const __attribute__((address_space(1))) void*)g,
        (__attribute__((address_space(3))) void*)l, 16, 0, 0);
}

// ---------------- fp32 -> bf16 conversion, exact-size grid (8192 blocks) ----------------
__global__ void cvt6(const float* __restrict__ x, const float* __restrict__ wq,
                     const float* __restrict__ wk, const float* __restrict__ wv,
                     const float* __restrict__ wp,
                     short* __restrict__ xo, short* __restrict__ qo,
                     short* __restrict__ ko, short* __restrict__ vo,
                     short* __restrict__ po) {
    const int bx = blockIdx.x;
    const float* in; short* out; int ib;
    if (bx < 4096) { in = x; out = xo; ib = bx; }
    else {
        const int r = bx - 4096, w = r >> 10;
        ib = r & 1023;
        switch (w) {
            case 0: in = wq; out = qo; break;
            case 1: in = wk; out = ko; break;
            case 2: in = wv; out = vo; break;
            default: in = wp; out = po; break;
        }
    }
    const int i = ib * 1024 + threadIdx.x * 4;
    float4 v = *(const float4*)(in + i);
    int2 o;
    o.x = (int)pack2_rn(v.x, v.y);
    o.y = (int)pack2_rn(v.z, v.w);
    *(int2*)(out + i) = o;
}

// ---------------- fused QKV GEMM (m97 structure) ----------------
// out[m,n] = sum_k X[m,k]*W[n,k] + b[n].  BM=BN=128, BK=32, 256 thr, wave=64x64.
// z=0: Q (bf16, *QSCALE), z=1: K (bf16), z=2: V -> Vt[(b*1024+ch)*T + t] (bf16,
// via LDS-transpose epilogue with coalesced stores).
__global__ __launch_bounds__(256, 3) void qkv_gemm(
    const short* __restrict__ X,
    const short* __restrict__ Wq, const short* __restrict__ Wk, const short* __restrict__ Wv,
    const float* __restrict__ bq, const float* __restrict__ bk, const float* __restrict__ bv,
    short* __restrict__ Qo, short* __restrict__ Ko, short* __restrict__ Vto)
{
    const int z = blockIdx.z;
    const short* W = (z == 0) ? Wq : (z == 1) ? Wk : Wv;
    const float* bias = (z == 0) ? bq : (z == 1) ? bk : bv;

    __shared__ __align__(16) short Ash[128 * 32];
    __shared__ __align__(16) short Bsh[128 * 32];
    __shared__ __align__(16) short TR[64 * 72];   // transpose staging (z==2 epilogue)

    const int tid = threadIdx.x, lane = tid & 63, wave = tid >> 6;
    const int ln = lane & 15, hi = lane >> 4;
    const int m0 = blockIdx.x * 128, n0 = blockIdx.y * 128;
    const int wm = (wave >> 1) * 64, wn = (wave & 1) * 64;

    const short* Ag = X + (size_t)(m0 + (tid >> 2)) * Csz + (tid & 3) * 8;
    const short* Bg = W + (size_t)(n0 + (tid >> 2)) * Csz + (tid & 3) * 8;

    f4v acc[4][4];
    #pragma unroll
    for (int mt = 0; mt < 4; mt++)
        #pragma unroll
        for (int nt = 0; nt < 4; nt++)
            #pragma unroll
            for (int i = 0; i < 4; i++) acc[mt][nt][i] = 0.f;

    for (int k0 = 0; k0 < Csz; k0 += 32) {
        __syncthreads();
        gload_lds(Ag + k0, Ash + tid * 8);
        gload_lds(Ag + k0 + (size_t)64 * Csz, Ash + 2048 + tid * 8);
        gload_lds(Bg + k0, Bsh + tid * 8);
        gload_lds(Bg + k0 + (size_t)64 * Csz, Bsh + 2048 + tid * 8);
        __syncthreads();

        s8v af[4], bfr_[4];
        #pragma unroll
        for (int mt = 0; mt < 4; mt++)
            af[mt] = *(const s8v*)(Ash + (wm + mt * 16 + ln) * 32 + hi * 8);
        #pragma unroll
        for (int nt = 0; nt < 4; nt++)
            bfr_[nt] = *(const s8v*)(Bsh + (wn + nt * 16 + ln) * 32 + hi * 8);
        #pragma unroll
        for (int mt = 0; mt < 4; mt++)
            #pragma unroll
            for (int nt = 0; nt < 4; nt++)
                acc[mt][nt] = __builtin_amdgcn_mfma_f32_16x16x32_bf16(af[mt], bfr_[nt], acc[mt][nt], 0, 0, 0);
    }

    if (z == 2) {
        // LDS-transpose epilogue: 4 passes, each pass covers (m-half, n-half).
        const int b = m0 >> 11, t0 = m0 & 2047;
        float bvv[4];
        #pragma unroll
        for (int nt = 0; nt < 4; nt++) bvv[nt] = bias[n0 + wn + nt * 16 + ln];
        #pragma unroll
        for (int ph = 0; ph < 4; ph++) {
            const int mh = ph >> 1, nh = ph & 1;
            __syncthreads();
            if ((wave >> 1) == mh && (wave & 1) == nh) {
                #pragma unroll
                for (int mt = 0; mt < 4; mt++)
                    #pragma unroll
                    for (int nt = 0; nt < 4; nt++) {
                        int2 pk;
                        pk.x = (int)pack2_rn(acc[mt][nt][0] + bvv[nt], acc[mt][nt][1] + bvv[nt]);
                        pk.y = (int)pack2_rn(acc[mt][nt][2] + bvv[nt], acc[mt][nt][3] + bvv[nt]);
                        *(int2*)(TR + (nt * 16 + ln) * 72 + mt * 16 + hi * 4) = pk;
                    }
            }
            __syncthreads();
            const int chl = tid >> 2, seg = tid & 3;   // 64 ch rows x 4 t-segments
            const s8v r0 = *(const s8v*)(TR + chl * 72 + seg * 16);
            const s8v r1 = *(const s8v*)(TR + chl * 72 + seg * 16 + 8);
            short* dst = Vto + (size_t)(b * 1024 + n0 + nh * 64 + chl) * Tsz + t0 + mh * 64 + seg * 16;
            *(s8v*)(dst) = r0;
            *(s8v*)(dst + 8) = r1;
        }
        return;
    }

    const float scale = (z == 0) ? QSCALE : 1.0f;
    short* out = (z == 0) ? Qo : Ko;

    #pragma unroll
    for (int nt = 0; nt < 4; nt++) {
        const int col = n0 + wn + nt * 16 + ln;
        const float bvv = bias[col];
        #pragma unroll
        for (int mt = 0; mt < 4; mt++) {
            const int row0 = m0 + wm + mt * 16 + hi * 4;
            #pragma unroll
            for (int i = 0; i < 4; i++)
                out[(size_t)(row0 + i) * Csz + col] = (short)bfr((acc[mt][nt][i] + bvv) * scale);
        }
    }
}

// ---------------- output projection GEMM (f32 out), 128x64 tiles, grid (32,16) ----------------
__global__ __launch_bounds__(256, 2) void proj_gemm(
    const short* __restrict__ A, const short* __restrict__ W,
    const float* __restrict__ bias, float* __restrict__ out)
{
    __shared__ __align__(16) short Ash[128 * 32];
    __shared__ __align__(16) short Bsh[64 * 32];

    const int tid = threadIdx.x, lane = tid & 63, wave = tid >> 6;
    const int ln = lane & 15, hi = lane >> 4;
    const int m0 = blockIdx.x * 128, n0 = blockIdx.y * 64;
    const int wm = (wave >> 1) * 64, wn = (wave & 1) * 32;

    const short* Ag = A + (size_t)(m0 + (tid >> 2)) * Csz + (tid & 3) * 8;
    const short* Bg = W + (size_t)(n0 + (tid >> 2)) * Csz + (tid & 3) * 8;

    f4v acc[4][2];
    #pragma unroll
    for (int mt = 0; mt < 4; mt++)
        #pragma unroll
        for (int nt = 0; nt < 2; nt++)
            #pragma unroll
            for (int i = 0; i < 4; i++) acc[mt][nt][i] = 0.f;

    for (int k0 = 0; k0 < Csz; k0 += 32) {
        __syncthreads();
        gload_lds(Ag + k0, Ash + tid * 8);
        gload_lds(Ag + k0 + (size_t)64 * Csz, Ash + 2048 + tid * 8);
        gload_lds(Bg + k0, Bsh + tid * 8);
        __syncthreads();

        s8v af[4], bfr_[2];
        #pragma unroll
        for (int mt = 0; mt < 4; mt++)
            af[mt] = *(const s8v*)(Ash + (wm + mt * 16 + ln) * 32 + hi * 8);
        #pragma unroll
        for (int nt = 0; nt < 2; nt++)
            bfr_[nt] = *(const s8v*)(Bsh + (wn + nt * 16 + ln) * 32 + hi * 8);
        #pragma unroll
        for (int mt = 0; mt < 4; mt++)
            #pragma unroll
            for (int nt = 0; nt < 2; nt++)
                acc[mt][nt] = __builtin_amdgcn_mfma_f32_16x16x32_bf16(af[mt], bfr_[nt], acc[mt][nt], 0, 0, 0);
    }

    #pragma unroll
    for (int nt = 0; nt < 2; nt++) {
        const int col = n0 + wn + nt * 16 + ln;
        const float bvv = bias[col];
        #pragma unroll
        for (int mt = 0; mt < 4; mt++)
            #pragma unroll
            for (int i = 0; i < 4; i++)
                out[(size_t)(m0 + wm + mt * 16 + hi * 4 + i) * Csz + col] = acc[mt][nt][i] + bvv;
    }
}

// ---------------- Flash attention v9 (attn7 + fast bf16 pack) ----
// Q,K: [B,T,C] bf16; Vt: [B*H*64, T] bf16; Y: [B,T,C] bf16.
// St = K*Q^T, O^T = Vt*P^T; P^T re-laid out via wave-private LDS.
// Block: 512 thr = 8 waves = 2 groups; group 0 handles q-tiles {p, 31-p},
// group 1 handles {15-p, 16+p} (p = blockIdx.x in 0..7); staging shared by both.
// K/V LDS double-buffered: one __syncthreads per key-tile iteration.
__global__ __launch_bounds__(512, 2) void attn9(
    const short* __restrict__ Q, const short* __restrict__ Kg,
    const short* __restrict__ Vt, short* __restrict__ Y)
{
    __shared__ __align__(16) short Ksh[2][64 * 72];  // [buf][key][d], pitch 72
    __shared__ __align__(16) short Vsh[2][64 * 72];  // [buf][d][key], pitch 72
    __shared__ __align__(16) short Psh[8][16 * 72];  // per-wave Pq[q][key]

    const int tid = threadIdx.x, lane = tid & 63, wave = tid >> 6;
    const int wv = wave & 3, g = wave >> 2;
    const int ln = lane & 15, hi = lane >> 4;
    const int p = blockIdx.x;                 // 0..7
    const int qts[2] = { g ? 15 - p : p, g ? 16 + p : 31 - p };  // light, heavy
    const int bh = blockIdx.y;
    const size_t base = (size_t)(bh >> 4) * Tsz * Csz + (size_t)(bh & 15) * 64;
    const size_t vtbase = (size_t)bh * 64 * Tsz;
    const int qrel = wv * 16 + ln;            // within-tile q row (MFMA n-col)
    short* Pq = Psh[wave];

    s8v qf[2][2];
    #pragma unroll
    for (int t = 0; t < 2; t++)
        #pragma unroll
        for (int kk = 0; kk < 2; kk++)
            qf[t][kk] = *(const s8v*)(Q + base + (size_t)(qts[t] * 64 + qrel) * Csz + kk * 32 + hi * 8);

    f4v o[2][4];
    float lsum[2] = {0.f, 0.f};
    #pragma unroll
    for (int t = 0; t < 2; t++)
        #pragma unroll
        for (int dt = 0; dt < 4; dt++)
            #pragma unroll
            for (int i = 0; i < 4; i++) o[t][dt][i] = 0.f;

    // staging: 512 threads, each 16 B of K and 16 B of V per tile
    const int sr = tid >> 3, sc = (tid & 7) * 8;
    const short* Kp = Kg + base + (size_t)sr * Csz + sc;
    const short* Vp = Vt + vtbase + (size_t)sr * Tsz + sc;
    const int swo = sr * 72 + sc;

    const int nkb = 32 - p;                   // covers both groups' needs

    // prologue: tile0 -> buf0; prefetch tile1 into regs
    s8v kR = *(const s8v*)(Kp);
    s8v vR = *(const s8v*)(Vp);
    *(s8v*)(&Ksh[0][swo]) = kR;
    *(s8v*)(&Vsh[0][swo]) = vR;
    kR = *(const s8v*)(Kp + (size_t)64 * Csz);
    vR = *(const s8v*)(Vp + 64);
    __syncthreads();

    for (int kb = 0; kb < nkb; kb++) {
        const int buf = kb & 1;
        if (kb + 1 < nkb) {
            // stage tile kb+1 into the other buffer; prefetch tile kb+2
            *(s8v*)(&Ksh[buf ^ 1][swo]) = kR;
            *(s8v*)(&Vsh[buf ^ 1][swo]) = vR;
            const int knx = (kb + 2 < nkb) ? (kb + 2) * 64 : (nkb - 1) * 64;
            kR = *(const s8v*)(Kp + (size_t)knx * Csz);
            vR = *(const s8v*)(Vp + knx);
        }

        s8v kf[2][4], vf[2][4];
        #pragma unroll
        for (int nt = 0; nt < 4; nt++)
            #pragma unroll
            for (int kk = 0; kk < 2; kk++) {
                kf[kk][nt] = *(const s8v*)(&Ksh[buf][(nt * 16 + ln) * 72 + kk * 32 + hi * 8]);
                vf[kk][nt] = *(const s8v*)(&Vsh[buf][(nt * 16 + ln) * 72 + kk * 32 + hi * 8]);
            }

        #pragma unroll
        for (int t = 0; t < 2; t++) {
            if (kb > qts[t]) continue;         // wave-uniform
            const bool dg = (kb == qts[t]);    // diagonal block for this tile

            f4v s[4];
            #pragma unroll
            for (int nt = 0; nt < 4; nt++) {
                #pragma unroll
                for (int i = 0; i < 4; i++) s[nt][i] = 0.f;
                s[nt] = __builtin_amdgcn_mfma_f32_16x16x32_bf16(kf[0][nt], qf[t][0], s[nt], 0, 0, 0);
                s[nt] = __builtin_amdgcn_mfma_f32_16x16x32_bf16(kf[1][nt], qf[t][1], s[nt], 0, 0, 0);
            }

            // P^T write: lane holds keys nt*16+hi*4+{0..3} for q=ln; l accumulated in VALU
            #pragma unroll
            for (int nt = 0; nt < 4; nt++) {
                float pv[4];
                #pragma unroll
                for (int i = 0; i < 4; i++) pv[i] = exp2f(s[nt][i]);
                if (dg) {
                    const int kr = nt * 16 + hi * 4;
                    #pragma unroll
                    for (int i = 0; i < 4; i++)
                        if (kr + i > qrel) pv[i] = 0.f;
                }
                lsum[t] += (pv[0] + pv[1]) + (pv[2] + pv[3]);
                int2 w;
                w.x = (int)pack2_rn(pv[0], pv[1]);
                w.y = (int)pack2_rn(pv[2], pv[3]);
                *(int2*)(Pq + ln * 72 + nt * 16 + hi * 4) = w;  // ds_write_b64
            }
            // B-frag read: keys kk*32+hi*8+{0..7} for q=ln
            const s8v pb0 = *(const s8v*)(Pq + ln * 72 + hi * 8);
            const s8v pb1 = *(const s8v*)(Pq + ln * 72 + 32 + hi * 8);

            #pragma unroll
            for (int dt = 0; dt < 4; dt++) {
                o[t][dt] = __builtin_amdgcn_mfma_f32_16x16x32_bf16(vf[0][dt], pb0, o[t][dt], 0, 0, 0);
                o[t][dt] = __builtin_amdgcn_mfma_f32_16x16x32_bf16(vf[1][dt], pb1, o[t][dt], 0, 0, 0);
            }
        }
        __syncthreads();
    }

    // l = sum over all keys for q=ln: reduce across the 4 hi-groups (lanes ln+16k)
    #pragma unroll
    for (int t = 0; t < 2; t++) {
        float l = lsum[t];
        l += __shfl_xor(l, 16);
        l += __shfl_xor(l, 32);
        const float inv = 1.0f / l;
        const int qrow = qts[t] * 64 + qrel;
        #pragma unroll
        for (int dt = 0; dt < 4; dt++) {
            int2 w;
            w.x = (int)pack2_rn(o[t][dt][0] * inv, o[t][dt][1] * inv);
            w.y = (int)pack2_rn(o[t][dt][2] * inv, o[t][dt][3] * inv);
            *(int2*)(Y + base + (size_t)qrow * Csz + dt * 16 + hi * 4) = w;
        }
    }
}

extern "C" void kernel_launch(void* const* d_in, const int* in_sizes, int n_in,
                              void* d_out, int out_size, void* d_ws, size_t ws_size,
                              hipStream_t stream) {
    const float* x  = (const float*)d_in[0];
    const float* Wq = (const float*)d_in[1];
    const float* bq = (const float*)d_in[2];
    const float* Wk = (const float*)d_in[3];
    const float* bk = (const float*)d_in[4];
    const float* Wv = (const float*)d_in[5];
    const float* bv = (const float*)d_in[6];
    const float* Wp = (const float*)d_in[7];
    const float* bp = (const float*)d_in[8];

    char* ws = (char*)d_ws;
    short* Xb  = (short*)(ws);                 // 8 MB
    short* Wqb = (short*)(ws + (8u  << 20));   // 2 MB each
    short* Wkb = (short*)(ws + (10u << 20));
    short* Wvb = (short*)(ws + (12u << 20));
    short* Wpb = (short*)(ws + (14u << 20));
    short* Qb  = (short*)(ws + (16u << 20));   // 8 MB each
    short* Kb  = (short*)(ws + (24u << 20));
    short* Vtb = (short*)(ws + (32u << 20));   // V transposed per head [B*H*64, T]
    short* Yb  = (short*)(ws + (40u << 20));

    hipLaunchKernelGGL(cvt6, dim3(8192), dim3(256), 0, stream,
                       x, Wq, Wk, Wv, Wp, Xb, Wqb, Wkb, Wvb, Wpb);

    hipLaunchKernelGGL(qkv_gemm, dim3(32, 8, 3), dim3(256), 0, stream,
                       Xb, Wqb, Wkb, Wvb, bq, bk, bv, Qb, Kb, Vtb);

    hipLaunchKernelGGL(attn9, dim3(8, 32), dim3(512), 0, stream, Qb, Kb, Vtb, Yb);

    hipLaunchKernelGGL(proj_gemm, dim3(32, 16), dim3(256), 0, stream, Yb, Wpb, bp, (float*)d_out);
}